// Round 6
// baseline (724.647 us; speedup 1.0000x reference)
//
#include <hip/hip_runtime.h>
#include <math.h>

#define NN 50000
#define NE 600000
#define HID 128
#define NCLS 10
#define T2S 16  // padded row stride for the 10-class intermediate

typedef __bf16 bf16x8 __attribute__((ext_vector_type(8)));
typedef float f32x16 __attribute__((ext_vector_type(16)));

// Exact 3-way bf16 split: f == hi + mid + lo (bit-truncation splits are exact;
// fp32 has 24 mantissa bits, 3x bf16 planes carry 8+8+8 = all of them).
__device__ __forceinline__ void split3(float f, ushort& h, ushort& m, ushort& l) {
    unsigned uh = __float_as_uint(f) & 0xffff0000u;
    float fm = f - __uint_as_float(uh);
    unsigned um = __float_as_uint(fm) & 0xffff0000u;
    float fl = fm - __uint_as_float(um);
    h = (ushort)(uh >> 16);
    m = (ushort)(um >> 16);
    l = (ushort)(__float_as_uint(fl) >> 16);
}

// ================= graph prep: CSR by destination =================

__global__ __launch_bounds__(256) void k_count(const int* __restrict__ edge,
                                               int* __restrict__ counts) {
    int e = blockIdx.x * 256 + threadIdx.x;
    if (e < NE) atomicAdd(&counts[edge[NE + e]], 1);
}

__device__ __forceinline__ int wave_incl_scan(int x, int lane) {
#pragma unroll
    for (int off = 1; off < 64; off <<= 1) {
        int y = __shfl_up(x, off, 64);
        if (lane >= off) x += y;
    }
    return x;
}

__global__ __launch_bounds__(256) void k_scan1(const int* __restrict__ counts,
                                               int* __restrict__ rowptr,
                                               int* __restrict__ bsum,
                                               float* __restrict__ dinv) {
    __shared__ int ws[4];
    int tid = threadIdx.x;
    int i = blockIdx.x * 256 + tid;
    int lane = tid & 63, wv = tid >> 6;
    int v = (i < NN) ? counts[i] : 0;
    if (i < NN) dinv[i] = rsqrtf((float)(v + 1));
    int x = wave_incl_scan(v, lane);
    if (lane == 63) ws[wv] = x;
    __syncthreads();
    int off = 0;
    for (int j = 0; j < wv; ++j) off += ws[j];
    if (i < NN) rowptr[i] = off + x - v;
    if (tid == 255) bsum[blockIdx.x] = off + x;
}

__global__ __launch_bounds__(256) void k_scan2(int* __restrict__ bsum, int n) {
    __shared__ int ws[4];
    int tid = threadIdx.x;
    int lane = tid & 63, wv = tid >> 6;
    int v = (tid < n) ? bsum[tid] : 0;
    int x = wave_incl_scan(v, lane);
    if (lane == 63) ws[wv] = x;
    __syncthreads();
    int off = 0;
    for (int j = 0; j < wv; ++j) off += ws[j];
    __syncthreads();
    if (tid < n) bsum[tid] = off + x - v;
}

__global__ __launch_bounds__(256) void k_scan3(int* __restrict__ rowptr,
                                               const int* __restrict__ bsum) {
    int i = blockIdx.x * 256 + threadIdx.x;
    if (i < NN) rowptr[i] += bsum[blockIdx.x];
    if (i == 0) rowptr[NN] = NE;
}

// cursor == counts (still holds per-node counts after scan1); atomicSub gives
// slots count-1..0 -- order within a row is irrelevant for a sum.
__global__ __launch_bounds__(256) void k_fill(const int* __restrict__ edge,
                                              const int* __restrict__ rowptr,
                                              int* __restrict__ cursor,
                                              const float* __restrict__ dinv,
                                              int2* __restrict__ csr) {
    int e = blockIdx.x * 256 + threadIdx.x;
    if (e >= NE) return;
    int s = edge[e], d = edge[NE + e];
    int slot = atomicSub(&cursor[d], 1) - 1;
    csr[rowptr[d] + slot] = make_int2(s, __float_as_int(dinv[s] * dinv[d]));
}

// ================= one-time weight split =================
// W_stack [8][128 k][128 n] fp32 -> Wt4 [8][3 planes][8 ks][128 n][16] bf16.
// Inner 16 = k within the 16-k MFMA slice (lh*8 + j). A wave's B-fragment load
// for (plane, ks, colblock) is then 64 lanes x 16B = 1 KB fully contiguous.

__global__ __launch_bounds__(256) void k_split_w(const float* __restrict__ Wst,
                                                 ushort* __restrict__ Wt4) {
    int i = blockIdx.x * 256 + threadIdx.x;
    if (i >= 8 * HID * HID) return;
    int l = i >> 14;
    int k = (i >> 7) & 127;
    int n = i & 127;
    ushort h, m, lo;
    split3(Wst[i], h, m, lo);
    int ks = k >> 4, r = k & 15;
    // dest = (((l*3 + p)*8 + ks)*128 + n)*16 + r
    size_t base = ((((size_t)l * 3) * 8 + ks) * 128 + n) * 16 + r;
    const size_t pstride = (size_t)8 * 128 * 16;  // one plane = 16384 ushort
    Wt4[base] = h;
    Wt4[base + pstride] = m;
    Wt4[base + 2 * pstride] = lo;
}

// ========== dense: H[NN,128] fp32 @ W[128,128] -> T fp32, via bf16 MFMA ==========
// NO LDS, NO BARRIERS. Wave w owns rows [blk*128 + w*32, +32), all 128 cols.
// MFMA A-fragment (lane l31 = row, lane>>5 picks k-octet) is 8 CONSECUTIVE k
// of one row -> loaded per-lane straight from row-major H (2x float4), split
// to 3 bf16 planes in-register. B-fragments stream from Wt4 (L2-resident).
// 6 plane-products (hh, hm, mh, hl, mm, lh) reproduce fp32 accuracy.

__global__ __launch_bounds__(256) void k_mfma_gemm(const float* __restrict__ H,
                                                   const ushort* __restrict__ Wt,
                                                   float* __restrict__ T) {
    int tid = threadIdx.x;
    int lane = tid & 63, w = tid >> 6;
    int l31 = lane & 31, lh = lane >> 5;
    int rowbase = blockIdx.x * 128;

    int grow = rowbase + w * 32 + l31;
    if (grow >= NN) grow = NN - 1;  // clamp; stores predicated below
    const float* arow = H + (size_t)grow * HID + lh * 8;

    // per-lane base into Wt4: col = l31 (+32c), k-in-slice = lh*8
    const ushort* wbase = Wt + (size_t)l31 * 16 + lh * 8;

    f32x16 acc[4] = {};

#pragma unroll 2
    for (int s = 0; s < 8; ++s) {
        // ---- A: 8 consecutive fp32 of this lane's row, split to 3 planes ----
        const float4* ap = (const float4*)(arow + s * 16);
        float4 f0 = ap[0], f1 = ap[1];
        float av[8] = {f0.x, f0.y, f0.z, f0.w, f1.x, f1.y, f1.z, f1.w};
        union { ushort u[8]; bf16x8 v; } ah, am, al;
#pragma unroll
        for (int q = 0; q < 8; ++q) split3(av[q], ah.u[q], am.u[q], al.u[q]);

        // ---- B: 3 planes x 4 colblocks, coalesced 1KB/wave, L2-resident ----
        uint4 bf[3][4];
#pragma unroll
        for (int p = 0; p < 3; ++p)
#pragma unroll
            for (int c = 0; c < 4; ++c)
                bf[p][c] = *(const uint4*)(wbase + (((size_t)p * 8 + s) * 128 + c * 32) * 16);

        // ---- 6 plane products x 4 colblocks = 24 MFMA ----
#pragma unroll
        for (int c = 0; c < 4; ++c)
            acc[c] = __builtin_amdgcn_mfma_f32_32x32x16_bf16(ah.v, *(const bf16x8*)&bf[0][c], acc[c], 0, 0, 0);
#pragma unroll
        for (int c = 0; c < 4; ++c)
            acc[c] = __builtin_amdgcn_mfma_f32_32x32x16_bf16(ah.v, *(const bf16x8*)&bf[1][c], acc[c], 0, 0, 0);
#pragma unroll
        for (int c = 0; c < 4; ++c)
            acc[c] = __builtin_amdgcn_mfma_f32_32x32x16_bf16(am.v, *(const bf16x8*)&bf[0][c], acc[c], 0, 0, 0);
#pragma unroll
        for (int c = 0; c < 4; ++c)
            acc[c] = __builtin_amdgcn_mfma_f32_32x32x16_bf16(ah.v, *(const bf16x8*)&bf[2][c], acc[c], 0, 0, 0);
#pragma unroll
        for (int c = 0; c < 4; ++c)
            acc[c] = __builtin_amdgcn_mfma_f32_32x32x16_bf16(am.v, *(const bf16x8*)&bf[1][c], acc[c], 0, 0, 0);
#pragma unroll
        for (int c = 0; c < 4; ++c)
            acc[c] = __builtin_amdgcn_mfma_f32_32x32x16_bf16(al.v, *(const bf16x8*)&bf[0][c], acc[c], 0, 0, 0);
    }

    // C/D layout: col = lane&31, row = (reg&3) + 8*(reg>>2) + 4*(lane>>5)
#pragma unroll
    for (int c = 0; c < 4; ++c)
#pragma unroll
        for (int reg = 0; reg < 16; ++reg) {
            int r = (reg & 3) + 8 * (reg >> 2) + 4 * lh;
            int gr = rowbase + w * 32 + r;
            if (gr < NN)
                T[(size_t)gr * HID + c * 32 + l31] = acc[c][reg];
        }
}

// ============ sparse by gather: 64 lanes per node, 2 edge slots ============
// Each lane owns 4 columns (float4 at l31*4); slot = lane>>5 takes every other
// edge, unroll-4 with prefetch -> 8 row loads in flight per node. Slot 1 folds
// the self-term + bias into its acc; one shfl_xor(32) reduce; slot 0 does ELU+write.

__global__ __launch_bounds__(256) void k_gather_agg(const float* __restrict__ T,
                                                    float* __restrict__ Hout,
                                                    const int* __restrict__ rowptr,
                                                    const int2* __restrict__ csr,
                                                    const float* __restrict__ dinv,
                                                    const float* __restrict__ bias) {
    int lane = threadIdx.x & 63;
    int node = (blockIdx.x * 256 + threadIdx.x) >> 6;
    if (node >= NN) return;
    int slot = lane >> 5, l31 = lane & 31;

    int beg = rowptr[node], end = rowptr[node + 1];
    float sn = dinv[node];

    float4 acc = {0.f, 0.f, 0.f, 0.f};
    if (slot == 1) {
        float4 tv = ((const float4*)(T + (size_t)node * HID))[l31];
        float4 bv = ((const float4*)bias)[l31];
        float s2 = sn * sn;
        acc.x = s2 * tv.x + bv.x;
        acc.y = s2 * tv.y + bv.y;
        acc.z = s2 * tv.z + bv.z;
        acc.w = s2 * tv.w + bv.w;
    }

    const int2 zed = make_int2(0, 0);  // norm bits 0 -> weight 0 (reads row 0, harmless)
    int p = beg + slot;
    int2 e0 = (p < end) ? csr[p] : zed;
    int2 e1 = (p + 2 < end) ? csr[p + 2] : zed;
    int2 e2 = (p + 4 < end) ? csr[p + 4] : zed;
    int2 e3 = (p + 6 < end) ? csr[p + 6] : zed;
    for (; p < end; p += 8) {
        float4 u0 = ((const float4*)(T + (size_t)e0.x * HID))[l31];
        float4 u1 = ((const float4*)(T + (size_t)e1.x * HID))[l31];
        float4 u2 = ((const float4*)(T + (size_t)e2.x * HID))[l31];
        float4 u3 = ((const float4*)(T + (size_t)e3.x * HID))[l31];
        float w0 = __int_as_float(e0.y), w1 = __int_as_float(e1.y);
        float w2 = __int_as_float(e2.y), w3 = __int_as_float(e3.y);
        e0 = (p + 8 < end) ? csr[p + 8] : zed;
        e1 = (p + 10 < end) ? csr[p + 10] : zed;
        e2 = (p + 12 < end) ? csr[p + 12] : zed;
        e3 = (p + 14 < end) ? csr[p + 14] : zed;
        acc.x += w0 * u0.x; acc.y += w0 * u0.y; acc.z += w0 * u0.z; acc.w += w0 * u0.w;
        acc.x += w1 * u1.x; acc.y += w1 * u1.y; acc.z += w1 * u1.z; acc.w += w1 * u1.w;
        acc.x += w2 * u2.x; acc.y += w2 * u2.y; acc.z += w2 * u2.z; acc.w += w2 * u2.w;
        acc.x += w3 * u3.x; acc.y += w3 * u3.y; acc.z += w3 * u3.z; acc.w += w3 * u3.w;
    }

    acc.x += __shfl_xor(acc.x, 32, 64);
    acc.y += __shfl_xor(acc.y, 32, 64);
    acc.z += __shfl_xor(acc.z, 32, 64);
    acc.w += __shfl_xor(acc.w, 32, 64);

    if (slot == 0) {
        float4 r = acc;
        r.x = r.x > 0.f ? r.x : expm1f(r.x);
        r.y = r.y > 0.f ? r.y : expm1f(r.y);
        r.z = r.z > 0.f ? r.z : expm1f(r.z);
        r.w = r.w > 0.f ? r.w : expm1f(r.w);
        ((float4*)(Hout + (size_t)node * HID))[l31] = r;
    }
}

// ================= output layer (128 -> 10) =================
// Lane c16 owns 8 consecutive k (2 float4 loads); T2 rows padded to stride 16.

__global__ __launch_bounds__(256) void k_matmul_out(const float* __restrict__ H,
                                                    const float* __restrict__ W,
                                                    float* __restrict__ T2) {
    __shared__ float Ws[128 * 11];
    int tid = threadIdx.x;
    for (int m = tid; m < HID * NCLS; m += 256) {
        int k = m / NCLS, c = m - k * NCLS;
        Ws[k * 11 + c] = W[m];
    }
    __syncthreads();
    int row = (blockIdx.x * 256 + tid) >> 4;
    int c16 = tid & 15;
    if (row >= NN) return;
    const float4* h4 = (const float4*)(H + (size_t)row * HID) + c16 * 2;
    float4 h0 = h4[0], h1 = h4[1];
    float hv[8] = {h0.x, h0.y, h0.z, h0.w, h1.x, h1.y, h1.z, h1.w};
    float acc[NCLS];
#pragma unroll
    for (int c = 0; c < NCLS; ++c) acc[c] = 0.f;
#pragma unroll
    for (int j = 0; j < 8; ++j) {
        const float* wr = &Ws[(c16 * 8 + j) * 11];
#pragma unroll
        for (int c = 0; c < NCLS; ++c) acc[c] += hv[j] * wr[c];
    }
#pragma unroll
    for (int off = 8; off >= 1; off >>= 1) {
#pragma unroll
        for (int c = 0; c < NCLS; ++c) acc[c] += __shfl_xor(acc[c], off, 16);
    }
    if (c16 < NCLS) T2[(size_t)row * T2S + c16] = acc[c16];
}

__global__ __launch_bounds__(256) void k_gather_out(const float* __restrict__ T2,
                                                    float* __restrict__ out,
                                                    const int* __restrict__ rowptr,
                                                    const int2* __restrict__ csr,
                                                    const float* __restrict__ dinv,
                                                    const float* __restrict__ bias) {
    int lane = threadIdx.x & 63;
    int node = (blockIdx.x * 256 + threadIdx.x) >> 6;
    if (node >= NN) return;
    int slot = lane >> 4, c = lane & 15;
    int beg = rowptr[node], end = rowptr[node + 1];
    float acc = 0.f;
    if (c < NCLS) {
        for (int i = beg + slot; i < end; i += 4) {
            int2 e = csr[i];
            acc += __int_as_float(e.y) * T2[(size_t)e.x * T2S + c];
        }
    }
    acc += __shfl_xor(acc, 16, 64);
    acc += __shfl_xor(acc, 32, 64);
    if (slot == 0 && c < NCLS) {
        float sn = dinv[node];
        sn *= sn;
        out[node * NCLS + c] = acc + sn * T2[(size_t)node * T2S + c] + bias[c];
    }
}

// ================= launch =================

extern "C" void kernel_launch(void* const* d_in, const int* in_sizes, int n_in,
                              void* d_out, int out_size, void* d_ws, size_t ws_size,
                              hipStream_t stream) {
    (void)in_sizes; (void)n_in; (void)out_size; (void)ws_size;
    const float* x       = (const float*)d_in[0];
    const int*   edge    = (const int*)d_in[1];   // [2, NE] int32
    const float* W_stack = (const float*)d_in[2];
    const float* b_stack = (const float*)d_in[3];
    const float* W_out   = (const float*)d_in[4];
    const float* b_out   = (const float*)d_in[5];
    float* out = (float*)d_out;

    char* ws = (char*)d_ws;
    const size_t bigbuf = (size_t)NN * HID * sizeof(float);  // 25.6 MB
    float* X      = (float*)ws;
    float* Y      = (float*)(ws + bigbuf);
    char*  p      = ws + 2 * bigbuf;
    int2*  csr    = (int2*)p;              p += sizeof(int2) * NE;
    float* dinv   = (float*)p;             p += sizeof(float) * NN;
    int*   rowptr = (int*)p;               p += sizeof(int) * (NN + 1);
    int*   counts = (int*)p;               p += sizeof(int) * NN;    // reused as cursor
    int*   bsum   = (int*)p;               p += sizeof(int) * 256;
    p = (char*)(((size_t)p + 15) & ~(size_t)15);
    ushort* Wt4 = (ushort*)p;  p += sizeof(ushort) * 8 * 3 * HID * HID;  // 786 KB

    const int NB_N  = (NN + 255) / 256;
    const int NB_E  = (NE + 255) / 256;
    const int NB_G  = (NN + 127) / 128;        // 391 MFMA-GEMM tiles
    const int NB_A  = (NN * 64 + 255) / 256;   // 64 lanes per node
    const int NB_W  = (NN * 64 + 255) / 256;   // one wave per node (out layer)
    const int NB_O  = (NN * 16 + 255) / 256;
    const int NB_SW = (8 * HID * HID + 255) / 256;

    // ---- CSR build (per call) ----
    hipMemsetAsync(counts, 0, sizeof(int) * NN, stream);
    k_count<<<NB_E, 256, 0, stream>>>(edge, counts);
    k_scan1<<<NB_N, 256, 0, stream>>>(counts, rowptr, bsum, dinv);
    k_scan2<<<1, 256, 0, stream>>>(bsum, NB_N);
    k_scan3<<<NB_N, 256, 0, stream>>>(rowptr, bsum);
    k_fill<<<NB_E, 256, 0, stream>>>(edge, rowptr, counts, dinv, csr);

    // ---- one-time weight split ----
    k_split_w<<<NB_SW, 256, 0, stream>>>(W_stack, Wt4);

    // ---- 8 hidden layers ----
    const float* Hin = x;
    for (int l = 0; l < 8; ++l) {
        k_mfma_gemm<<<NB_G, 256, 0, stream>>>(Hin, Wt4 + (size_t)l * 3 * HID * HID, Y);
        k_gather_agg<<<NB_A, 256, 0, stream>>>(Y, X, rowptr, csr, dinv,
                                               b_stack + (size_t)l * HID);
        Hin = X;
    }

    // ---- output layer ----
    k_matmul_out<<<NB_O, 256, 0, stream>>>(X, W_out, Y);
    k_gather_out<<<NB_W, 256, 0, stream>>>(Y, out, rowptr, csr, dinv, b_out);
}

// Round 7
// 685.428 us; speedup vs baseline: 1.0572x; 1.0572x over previous
//
#include <hip/hip_runtime.h>
#include <math.h>

#define NN 50000
#define NE 600000
#define HID 128
#define NCLS 10
#define T2S 16  // padded row stride for the 10-class intermediate

typedef __bf16 bf16x8 __attribute__((ext_vector_type(8)));
typedef float f32x16 __attribute__((ext_vector_type(16)));

// Exact 3-way bf16 split: f == hi + mid + lo (bit-truncation splits are exact;
// fp32 has 24 mantissa bits, 3x bf16 planes carry 8+8+8 = all of them).
__device__ __forceinline__ void split3(float f, ushort& h, ushort& m, ushort& l) {
    unsigned uh = __float_as_uint(f) & 0xffff0000u;
    float fm = f - __uint_as_float(uh);
    unsigned um = __float_as_uint(fm) & 0xffff0000u;
    float fl = fm - __uint_as_float(um);
    h = (ushort)(uh >> 16);
    m = (ushort)(um >> 16);
    l = (ushort)(__float_as_uint(fl) >> 16);
}

// ================= graph prep: CSR by destination =================

__global__ __launch_bounds__(256) void k_count(const int* __restrict__ edge,
                                               int* __restrict__ counts) {
    int e = blockIdx.x * 256 + threadIdx.x;
    if (e < NE) atomicAdd(&counts[edge[NE + e]], 1);
}

__device__ __forceinline__ int wave_incl_scan(int x, int lane) {
#pragma unroll
    for (int off = 1; off < 64; off <<= 1) {
        int y = __shfl_up(x, off, 64);
        if (lane >= off) x += y;
    }
    return x;
}

__global__ __launch_bounds__(256) void k_scan1(const int* __restrict__ counts,
                                               int* __restrict__ rowptr,
                                               int* __restrict__ bsum,
                                               float* __restrict__ dinv) {
    __shared__ int ws[4];
    int tid = threadIdx.x;
    int i = blockIdx.x * 256 + tid;
    int lane = tid & 63, wv = tid >> 6;
    int v = (i < NN) ? counts[i] : 0;
    if (i < NN) dinv[i] = rsqrtf((float)(v + 1));
    int x = wave_incl_scan(v, lane);
    if (lane == 63) ws[wv] = x;
    __syncthreads();
    int off = 0;
    for (int j = 0; j < wv; ++j) off += ws[j];
    if (i < NN) rowptr[i] = off + x - v;
    if (tid == 255) bsum[blockIdx.x] = off + x;
}

__global__ __launch_bounds__(256) void k_scan2(int* __restrict__ bsum, int n) {
    __shared__ int ws[4];
    int tid = threadIdx.x;
    int lane = tid & 63, wv = tid >> 6;
    int v = (tid < n) ? bsum[tid] : 0;
    int x = wave_incl_scan(v, lane);
    if (lane == 63) ws[wv] = x;
    __syncthreads();
    int off = 0;
    for (int j = 0; j < wv; ++j) off += ws[j];
    __syncthreads();
    if (tid < n) bsum[tid] = off + x - v;
}

__global__ __launch_bounds__(256) void k_scan3(int* __restrict__ rowptr,
                                               const int* __restrict__ bsum) {
    int i = blockIdx.x * 256 + threadIdx.x;
    if (i < NN) rowptr[i] += bsum[blockIdx.x];
    if (i == 0) rowptr[NN] = NE;
}

// cursor == counts (still holds per-node counts after scan1); atomicSub gives
// slots count-1..0 -- order within a row is irrelevant for a sum.
__global__ __launch_bounds__(256) void k_fill(const int* __restrict__ edge,
                                              const int* __restrict__ rowptr,
                                              int* __restrict__ cursor,
                                              const float* __restrict__ dinv,
                                              int2* __restrict__ csr) {
    int e = blockIdx.x * 256 + threadIdx.x;
    if (e >= NE) return;
    int s = edge[e], d = edge[NE + e];
    int slot = atomicSub(&cursor[d], 1) - 1;
    csr[rowptr[d] + slot] = make_int2(s, __float_as_int(dinv[s] * dinv[d]));
}

// ================= one-time weight split =================
// W_stack [8][128 k][128 n] fp32 -> Wt4 [8][3 planes][8 ks][128 n][16] bf16.
// Inner 16 = k within the 16-k MFMA slice (lh*8 + j). A wave's B-fragment load
// for (plane, ks, colblock) is then 64 lanes x 16B = 1 KB fully contiguous.

__global__ __launch_bounds__(256) void k_split_w(const float* __restrict__ Wst,
                                                 ushort* __restrict__ Wt4) {
    int i = blockIdx.x * 256 + threadIdx.x;
    if (i >= 8 * HID * HID) return;
    int l = i >> 14;
    int k = (i >> 7) & 127;
    int n = i & 127;
    ushort h, m, lo;
    split3(Wst[i], h, m, lo);
    int ks = k >> 4, r = k & 15;
    size_t base = ((((size_t)l * 3) * 8 + ks) * 128 + n) * 16 + r;
    const size_t pstride = (size_t)8 * 128 * 16;  // one plane = 16384 ushort
    Wt4[base] = h;
    Wt4[base + pstride] = m;
    Wt4[base + 2 * pstride] = lo;
}

// ========== standalone dense GEMM (layer 0 only): H[NN,128] @ W -> T ==========
// Round-6 structure: no LDS, wave owns 32 rows x 128 cols, A per-lane from
// row-major H, split3 in-register; B streams from Wt4 (L2-resident).

__global__ __launch_bounds__(256) void k_mfma_gemm(const float* __restrict__ H,
                                                   const ushort* __restrict__ Wt,
                                                   float* __restrict__ T) {
    int tid = threadIdx.x;
    int lane = tid & 63, w = tid >> 6;
    int l31 = lane & 31, lh = lane >> 5;
    int rowbase = blockIdx.x * 128;

    int grow = rowbase + w * 32 + l31;
    if (grow >= NN) grow = NN - 1;
    const float* arow = H + (size_t)grow * HID + lh * 8;
    const ushort* wbase = Wt + (size_t)l31 * 16 + lh * 8;

    f32x16 acc[4] = {};

#pragma unroll 2
    for (int s = 0; s < 8; ++s) {
        const float4* ap = (const float4*)(arow + s * 16);
        float4 f0 = ap[0], f1 = ap[1];
        float av[8] = {f0.x, f0.y, f0.z, f0.w, f1.x, f1.y, f1.z, f1.w};
        union { ushort u[8]; bf16x8 v; } ah, am, al;
#pragma unroll
        for (int q = 0; q < 8; ++q) split3(av[q], ah.u[q], am.u[q], al.u[q]);

        uint4 bf[3][4];
#pragma unroll
        for (int p = 0; p < 3; ++p)
#pragma unroll
            for (int c = 0; c < 4; ++c)
                bf[p][c] = *(const uint4*)(wbase + (((size_t)p * 8 + s) * 128 + c * 32) * 16);

#pragma unroll
        for (int c = 0; c < 4; ++c)
            acc[c] = __builtin_amdgcn_mfma_f32_32x32x16_bf16(ah.v, *(const bf16x8*)&bf[0][c], acc[c], 0, 0, 0);
#pragma unroll
        for (int c = 0; c < 4; ++c)
            acc[c] = __builtin_amdgcn_mfma_f32_32x32x16_bf16(ah.v, *(const bf16x8*)&bf[1][c], acc[c], 0, 0, 0);
#pragma unroll
        for (int c = 0; c < 4; ++c)
            acc[c] = __builtin_amdgcn_mfma_f32_32x32x16_bf16(am.v, *(const bf16x8*)&bf[0][c], acc[c], 0, 0, 0);
#pragma unroll
        for (int c = 0; c < 4; ++c)
            acc[c] = __builtin_amdgcn_mfma_f32_32x32x16_bf16(ah.v, *(const bf16x8*)&bf[2][c], acc[c], 0, 0, 0);
#pragma unroll
        for (int c = 0; c < 4; ++c)
            acc[c] = __builtin_amdgcn_mfma_f32_32x32x16_bf16(am.v, *(const bf16x8*)&bf[1][c], acc[c], 0, 0, 0);
#pragma unroll
        for (int c = 0; c < 4; ++c)
            acc[c] = __builtin_amdgcn_mfma_f32_32x32x16_bf16(al.v, *(const bf16x8*)&bf[0][c], acc[c], 0, 0, 0);
    }

#pragma unroll
    for (int c = 0; c < 4; ++c)
#pragma unroll
        for (int reg = 0; reg < 16; ++reg) {
            int r = (reg & 3) + 8 * (reg >> 2) + 4 * lh;
            int gr = rowbase + w * 32 + r;
            if (gr < NN)
                T[(size_t)gr * HID + c * 32 + l31] = acc[c][reg];
        }
}

// ========== FUSED: gather(layer l) -> H in LDS -> GEMM W_{l+1} -> Tout ==========
// 512 threads, 128 nodes/block. Phase 1: wave w gathers nodes [16w,16w+16)
// (2 slots x 32 lanes, unroll-4 prefetch, bias+ELU), writes fp32 rows to LDS
// with per-16B-chunk XOR swizzle (byte ^= (row&7)<<4) -> conflict-free both ways.
// Phase 2: wave w = rowgroup (w>>1) x colhalf (w&1): 32 rows x 64 cols, A from
// LDS + split3 in-register, B streamed from Wt4. H never touches global memory.

__global__ __launch_bounds__(512, 4) void k_fused(const float* __restrict__ Tin,
                                                  const ushort* __restrict__ Wt,
                                                  const int* __restrict__ rowptr,
                                                  const int2* __restrict__ csr,
                                                  const float* __restrict__ dinv,
                                                  const float* __restrict__ bias,
                                                  float* __restrict__ Tout) {
    __shared__ float Hs[128 * 128];  // 64 KB
    int tid = threadIdx.x;
    int lane = tid & 63, w = tid >> 6;  // 8 waves
    int slot = lane >> 5, l31 = lane & 31;
    int rowbase = blockIdx.x * 128;

    float4 bv = ((const float4*)bias)[l31];

    // ---- phase 1: gather ----
    for (int i = 0; i < 16; ++i) {
        int lrow = w * 16 + i;
        int node = rowbase + lrow;
        if (node >= NN) node = NN - 1;
        int beg = rowptr[node], end = rowptr[node + 1];
        float sn = dinv[node];

        float4 acc = {0.f, 0.f, 0.f, 0.f};
        if (slot == 1) {
            float4 tv = ((const float4*)(Tin + (size_t)node * HID))[l31];
            float s2 = sn * sn;
            acc.x = s2 * tv.x + bv.x;
            acc.y = s2 * tv.y + bv.y;
            acc.z = s2 * tv.z + bv.z;
            acc.w = s2 * tv.w + bv.w;
        }

        const int2 zed = make_int2(0, 0);
        int p = beg + slot;
        int2 e0 = (p < end) ? csr[p] : zed;
        int2 e1 = (p + 2 < end) ? csr[p + 2] : zed;
        int2 e2 = (p + 4 < end) ? csr[p + 4] : zed;
        int2 e3 = (p + 6 < end) ? csr[p + 6] : zed;
        for (; p < end; p += 8) {
            float4 u0 = ((const float4*)(Tin + (size_t)e0.x * HID))[l31];
            float4 u1 = ((const float4*)(Tin + (size_t)e1.x * HID))[l31];
            float4 u2 = ((const float4*)(Tin + (size_t)e2.x * HID))[l31];
            float4 u3 = ((const float4*)(Tin + (size_t)e3.x * HID))[l31];
            float w0 = __int_as_float(e0.y), w1 = __int_as_float(e1.y);
            float w2 = __int_as_float(e2.y), w3 = __int_as_float(e3.y);
            e0 = (p + 8 < end) ? csr[p + 8] : zed;
            e1 = (p + 10 < end) ? csr[p + 10] : zed;
            e2 = (p + 12 < end) ? csr[p + 12] : zed;
            e3 = (p + 14 < end) ? csr[p + 14] : zed;
            acc.x += w0 * u0.x; acc.y += w0 * u0.y; acc.z += w0 * u0.z; acc.w += w0 * u0.w;
            acc.x += w1 * u1.x; acc.y += w1 * u1.y; acc.z += w1 * u1.z; acc.w += w1 * u1.w;
            acc.x += w2 * u2.x; acc.y += w2 * u2.y; acc.z += w2 * u2.z; acc.w += w2 * u2.w;
            acc.x += w3 * u3.x; acc.y += w3 * u3.y; acc.z += w3 * u3.z; acc.w += w3 * u3.w;
        }

        acc.x += __shfl_xor(acc.x, 32, 64);
        acc.y += __shfl_xor(acc.y, 32, 64);
        acc.z += __shfl_xor(acc.z, 32, 64);
        acc.w += __shfl_xor(acc.w, 32, 64);

        if (slot == 0) {
            float4 r = acc;
            r.x = r.x > 0.f ? r.x : expm1f(r.x);
            r.y = r.y > 0.f ? r.y : expm1f(r.y);
            r.z = r.z > 0.f ? r.z : expm1f(r.z);
            r.w = r.w > 0.f ? r.w : expm1f(r.w);
            int byte = lrow * 512 + l31 * 16;
            byte ^= (lrow & 7) << 4;
            *(float4*)((char*)Hs + byte) = r;
        }
    }
    __syncthreads();

    // ---- phase 2: GEMM 128x128 tile over 8 waves ----
    int lh = slot;                    // k-octet selector
    int rloc = (w >> 1) * 32 + l31;   // local A row
    int colh = w & 1;                 // column half (64)
    const ushort* wbase = Wt + ((size_t)(colh * 64) + l31) * 16 + lh * 8;

    f32x16 acc2[2] = {};

#pragma unroll 2
    for (int s = 0; s < 8; ++s) {
        int byte = rloc * 512 + s * 64 + lh * 32;
        int sw = (rloc & 7) << 4;
        float4 f0 = *(const float4*)((const char*)Hs + (byte ^ sw));
        float4 f1 = *(const float4*)((const char*)Hs + ((byte + 16) ^ sw));
        float av[8] = {f0.x, f0.y, f0.z, f0.w, f1.x, f1.y, f1.z, f1.w};
        union { ushort u[8]; bf16x8 v; } ah, am, al;
#pragma unroll
        for (int q = 0; q < 8; ++q) split3(av[q], ah.u[q], am.u[q], al.u[q]);

        uint4 bf[3][2];
#pragma unroll
        for (int p = 0; p < 3; ++p)
#pragma unroll
            for (int c = 0; c < 2; ++c)
                bf[p][c] = *(const uint4*)(wbase + (((size_t)p * 8 + s) * 128 + c * 32) * 16);

#pragma unroll
        for (int c = 0; c < 2; ++c)
            acc2[c] = __builtin_amdgcn_mfma_f32_32x32x16_bf16(ah.v, *(const bf16x8*)&bf[0][c], acc2[c], 0, 0, 0);
#pragma unroll
        for (int c = 0; c < 2; ++c)
            acc2[c] = __builtin_amdgcn_mfma_f32_32x32x16_bf16(ah.v, *(const bf16x8*)&bf[1][c], acc2[c], 0, 0, 0);
#pragma unroll
        for (int c = 0; c < 2; ++c)
            acc2[c] = __builtin_amdgcn_mfma_f32_32x32x16_bf16(am.v, *(const bf16x8*)&bf[0][c], acc2[c], 0, 0, 0);
#pragma unroll
        for (int c = 0; c < 2; ++c)
            acc2[c] = __builtin_amdgcn_mfma_f32_32x32x16_bf16(ah.v, *(const bf16x8*)&bf[2][c], acc2[c], 0, 0, 0);
#pragma unroll
        for (int c = 0; c < 2; ++c)
            acc2[c] = __builtin_amdgcn_mfma_f32_32x32x16_bf16(am.v, *(const bf16x8*)&bf[1][c], acc2[c], 0, 0, 0);
#pragma unroll
        for (int c = 0; c < 2; ++c)
            acc2[c] = __builtin_amdgcn_mfma_f32_32x32x16_bf16(al.v, *(const bf16x8*)&bf[0][c], acc2[c], 0, 0, 0);
    }

    // C/D layout: col = lane&31, row = (reg&3) + 8*(reg>>2) + 4*(lane>>5)
#pragma unroll
    for (int c = 0; c < 2; ++c)
#pragma unroll
        for (int reg = 0; reg < 16; ++reg) {
            int r = (reg & 3) + 8 * (reg >> 2) + 4 * lh;
            int gr = rowbase + (w >> 1) * 32 + r;
            if (gr < NN)
                Tout[(size_t)gr * HID + colh * 64 + c * 32 + l31] = acc2[c][reg];
        }
}

// ============ standalone gather (last hidden layer): T -> H global ============

__global__ __launch_bounds__(256) void k_gather_agg(const float* __restrict__ T,
                                                    float* __restrict__ Hout,
                                                    const int* __restrict__ rowptr,
                                                    const int2* __restrict__ csr,
                                                    const float* __restrict__ dinv,
                                                    const float* __restrict__ bias) {
    int lane = threadIdx.x & 63;
    int node = (blockIdx.x * 256 + threadIdx.x) >> 6;
    if (node >= NN) return;
    int slot = lane >> 5, l31 = lane & 31;

    int beg = rowptr[node], end = rowptr[node + 1];
    float sn = dinv[node];

    float4 acc = {0.f, 0.f, 0.f, 0.f};
    if (slot == 1) {
        float4 tv = ((const float4*)(T + (size_t)node * HID))[l31];
        float4 bv = ((const float4*)bias)[l31];
        float s2 = sn * sn;
        acc.x = s2 * tv.x + bv.x;
        acc.y = s2 * tv.y + bv.y;
        acc.z = s2 * tv.z + bv.z;
        acc.w = s2 * tv.w + bv.w;
    }

    const int2 zed = make_int2(0, 0);
    int p = beg + slot;
    int2 e0 = (p < end) ? csr[p] : zed;
    int2 e1 = (p + 2 < end) ? csr[p + 2] : zed;
    int2 e2 = (p + 4 < end) ? csr[p + 4] : zed;
    int2 e3 = (p + 6 < end) ? csr[p + 6] : zed;
    for (; p < end; p += 8) {
        float4 u0 = ((const float4*)(T + (size_t)e0.x * HID))[l31];
        float4 u1 = ((const float4*)(T + (size_t)e1.x * HID))[l31];
        float4 u2 = ((const float4*)(T + (size_t)e2.x * HID))[l31];
        float4 u3 = ((const float4*)(T + (size_t)e3.x * HID))[l31];
        float w0 = __int_as_float(e0.y), w1 = __int_as_float(e1.y);
        float w2 = __int_as_float(e2.y), w3 = __int_as_float(e3.y);
        e0 = (p + 8 < end) ? csr[p + 8] : zed;
        e1 = (p + 10 < end) ? csr[p + 10] : zed;
        e2 = (p + 12 < end) ? csr[p + 12] : zed;
        e3 = (p + 14 < end) ? csr[p + 14] : zed;
        acc.x += w0 * u0.x; acc.y += w0 * u0.y; acc.z += w0 * u0.z; acc.w += w0 * u0.w;
        acc.x += w1 * u1.x; acc.y += w1 * u1.y; acc.z += w1 * u1.z; acc.w += w1 * u1.w;
        acc.x += w2 * u2.x; acc.y += w2 * u2.y; acc.z += w2 * u2.z; acc.w += w2 * u2.w;
        acc.x += w3 * u3.x; acc.y += w3 * u3.y; acc.z += w3 * u3.z; acc.w += w3 * u3.w;
    }

    acc.x += __shfl_xor(acc.x, 32, 64);
    acc.y += __shfl_xor(acc.y, 32, 64);
    acc.z += __shfl_xor(acc.z, 32, 64);
    acc.w += __shfl_xor(acc.w, 32, 64);

    if (slot == 0) {
        float4 r = acc;
        r.x = r.x > 0.f ? r.x : expm1f(r.x);
        r.y = r.y > 0.f ? r.y : expm1f(r.y);
        r.z = r.z > 0.f ? r.z : expm1f(r.z);
        r.w = r.w > 0.f ? r.w : expm1f(r.w);
        ((float4*)(Hout + (size_t)node * HID))[l31] = r;
    }
}

// ================= output layer (128 -> 10) =================

__global__ __launch_bounds__(256) void k_matmul_out(const float* __restrict__ H,
                                                    const float* __restrict__ W,
                                                    float* __restrict__ T2) {
    __shared__ float Ws[128 * 11];
    int tid = threadIdx.x;
    for (int m = tid; m < HID * NCLS; m += 256) {
        int k = m / NCLS, c = m - k * NCLS;
        Ws[k * 11 + c] = W[m];
    }
    __syncthreads();
    int row = (blockIdx.x * 256 + tid) >> 4;
    int c16 = tid & 15;
    if (row >= NN) return;
    const float4* h4 = (const float4*)(H + (size_t)row * HID) + c16 * 2;
    float4 h0 = h4[0], h1 = h4[1];
    float hv[8] = {h0.x, h0.y, h0.z, h0.w, h1.x, h1.y, h1.z, h1.w};
    float acc[NCLS];
#pragma unroll
    for (int c = 0; c < NCLS; ++c) acc[c] = 0.f;
#pragma unroll
    for (int j = 0; j < 8; ++j) {
        const float* wr = &Ws[(c16 * 8 + j) * 11];
#pragma unroll
        for (int c = 0; c < NCLS; ++c) acc[c] += hv[j] * wr[c];
    }
#pragma unroll
    for (int off = 8; off >= 1; off >>= 1) {
#pragma unroll
        for (int c = 0; c < NCLS; ++c) acc[c] += __shfl_xor(acc[c], off, 16);
    }
    if (c16 < NCLS) T2[(size_t)row * T2S + c16] = acc[c16];
}

__global__ __launch_bounds__(256) void k_gather_out(const float* __restrict__ T2,
                                                    float* __restrict__ out,
                                                    const int* __restrict__ rowptr,
                                                    const int2* __restrict__ csr,
                                                    const float* __restrict__ dinv,
                                                    const float* __restrict__ bias) {
    int lane = threadIdx.x & 63;
    int node = (blockIdx.x * 256 + threadIdx.x) >> 6;
    if (node >= NN) return;
    int slot = lane >> 4, c = lane & 15;
    int beg = rowptr[node], end = rowptr[node + 1];
    float acc = 0.f;
    if (c < NCLS) {
        for (int i = beg + slot; i < end; i += 4) {
            int2 e = csr[i];
            acc += __int_as_float(e.y) * T2[(size_t)e.x * T2S + c];
        }
    }
    acc += __shfl_xor(acc, 16, 64);
    acc += __shfl_xor(acc, 32, 64);
    if (slot == 0 && c < NCLS) {
        float sn = dinv[node];
        sn *= sn;
        out[node * NCLS + c] = acc + sn * T2[(size_t)node * T2S + c] + bias[c];
    }
}

// ================= launch =================

extern "C" void kernel_launch(void* const* d_in, const int* in_sizes, int n_in,
                              void* d_out, int out_size, void* d_ws, size_t ws_size,
                              hipStream_t stream) {
    (void)in_sizes; (void)n_in; (void)out_size; (void)ws_size;
    const float* x       = (const float*)d_in[0];
    const int*   edge    = (const int*)d_in[1];   // [2, NE] int32
    const float* W_stack = (const float*)d_in[2];
    const float* b_stack = (const float*)d_in[3];
    const float* W_out   = (const float*)d_in[4];
    const float* b_out   = (const float*)d_in[5];
    float* out = (float*)d_out;

    char* ws = (char*)d_ws;
    const size_t bigbuf = (size_t)NN * HID * sizeof(float);  // 25.6 MB
    float* X      = (float*)ws;
    float* Y      = (float*)(ws + bigbuf);
    char*  p      = ws + 2 * bigbuf;
    int2*  csr    = (int2*)p;              p += sizeof(int2) * NE;
    float* dinv   = (float*)p;             p += sizeof(float) * NN;
    int*   rowptr = (int*)p;               p += sizeof(int) * (NN + 1);
    int*   counts = (int*)p;               p += sizeof(int) * NN;    // reused as cursor
    int*   bsum   = (int*)p;               p += sizeof(int) * 256;
    p = (char*)(((size_t)p + 15) & ~(size_t)15);
    ushort* Wt4 = (ushort*)p;  p += sizeof(ushort) * 8 * 3 * HID * HID;  // 786 KB
    float* T2b  = (float*)p;   p += sizeof(float) * NN * T2S;            // 3.2 MB

    const int NB_N  = (NN + 255) / 256;
    const int NB_E  = (NE + 255) / 256;
    const int NB_G  = (NN + 127) / 128;        // 391 tiles (GEMM + fused)
    const int NB_A  = (NN * 64 + 255) / 256;
    const int NB_O  = (NN * 16 + 255) / 256;
    const int NB_SW = (8 * HID * HID + 255) / 256;

    // ---- CSR build (per call) ----
    hipMemsetAsync(counts, 0, sizeof(int) * NN, stream);
    k_count<<<NB_E, 256, 0, stream>>>(edge, counts);
    k_scan1<<<NB_N, 256, 0, stream>>>(counts, rowptr, bsum, dinv);
    k_scan2<<<1, 256, 0, stream>>>(bsum, NB_N);
    k_scan3<<<NB_N, 256, 0, stream>>>(rowptr, bsum);
    k_fill<<<NB_E, 256, 0, stream>>>(edge, rowptr, counts, dinv, csr);

    // ---- one-time weight split ----
    k_split_w<<<NB_SW, 256, 0, stream>>>(W_stack, Wt4);

    // ---- layer 0 GEMM: T_0 = x . W0 ----
    k_mfma_gemm<<<NB_G, 256, 0, stream>>>(x, Wt4, Y);

    // ---- fused layers: gather(l) + GEMM W_{l+1}, l = 0..6 ----
    float* cur = Y;
    float* nxt = X;
    for (int l = 0; l < 7; ++l) {
        k_fused<<<NB_G, 512, 0, stream>>>(cur, Wt4 + (size_t)(l + 1) * 3 * HID * HID,
                                          rowptr, csr, dinv,
                                          b_stack + (size_t)l * HID, nxt);
        float* t = cur; cur = nxt; nxt = t;
    }

    // ---- last hidden gather (bias 7) -> H global ----
    k_gather_agg<<<NB_A, 256, 0, stream>>>(cur, nxt, rowptr, csr, dinv,
                                           b_stack + (size_t)7 * HID);

    // ---- output layer ----
    k_matmul_out<<<NB_O, 256, 0, stream>>>(nxt, W_out, T2b);
    k_gather_out<<<NB_A, 256, 0, stream>>>(T2b, out, rowptr, csr, dinv, b_out);
}

// Round 8
// 677.403 us; speedup vs baseline: 1.0697x; 1.0118x over previous
//
#include <hip/hip_runtime.h>
#include <math.h>

#define NN 50000
#define NE 600000
#define HID 128
#define NCLS 10
#define T2S 16  // padded row stride for the 10-class intermediate

typedef __bf16 bf16x8 __attribute__((ext_vector_type(8)));
typedef float f32x16 __attribute__((ext_vector_type(16)));

// Exact 3-way bf16 split: f == hi + mid + lo (bit-truncation splits are exact;
// fp32 has 24 mantissa bits, 3x bf16 planes carry 8+8+8 = all of them).
__device__ __forceinline__ void split3(float f, ushort& h, ushort& m, ushort& l) {
    unsigned uh = __float_as_uint(f) & 0xffff0000u;
    float fm = f - __uint_as_float(uh);
    unsigned um = __float_as_uint(fm) & 0xffff0000u;
    float fl = fm - __uint_as_float(um);
    h = (ushort)(uh >> 16);
    m = (ushort)(um >> 16);
    l = (ushort)(__float_as_uint(fl) >> 16);
}

// ================= graph prep: CSR by destination =================

__global__ __launch_bounds__(256) void k_count(const int* __restrict__ edge,
                                               int* __restrict__ counts) {
    int e = blockIdx.x * 256 + threadIdx.x;
    if (e < NE) atomicAdd(&counts[edge[NE + e]], 1);
}

__device__ __forceinline__ int wave_incl_scan(int x, int lane) {
#pragma unroll
    for (int off = 1; off < 64; off <<= 1) {
        int y = __shfl_up(x, off, 64);
        if (lane >= off) x += y;
    }
    return x;
}

__global__ __launch_bounds__(256) void k_scan1(const int* __restrict__ counts,
                                               int* __restrict__ rowptr,
                                               int* __restrict__ bsum,
                                               float* __restrict__ dinv) {
    __shared__ int ws[4];
    int tid = threadIdx.x;
    int i = blockIdx.x * 256 + tid;
    int lane = tid & 63, wv = tid >> 6;
    int v = (i < NN) ? counts[i] : 0;
    if (i < NN) dinv[i] = rsqrtf((float)(v + 1));
    int x = wave_incl_scan(v, lane);
    if (lane == 63) ws[wv] = x;
    __syncthreads();
    int off = 0;
    for (int j = 0; j < wv; ++j) off += ws[j];
    if (i < NN) rowptr[i] = off + x - v;
    if (tid == 255) bsum[blockIdx.x] = off + x;
}

__global__ __launch_bounds__(256) void k_scan2(int* __restrict__ bsum, int n) {
    __shared__ int ws[4];
    int tid = threadIdx.x;
    int lane = tid & 63, wv = tid >> 6;
    int v = (tid < n) ? bsum[tid] : 0;
    int x = wave_incl_scan(v, lane);
    if (lane == 63) ws[wv] = x;
    __syncthreads();
    int off = 0;
    for (int j = 0; j < wv; ++j) off += ws[j];
    __syncthreads();
    if (tid < n) bsum[tid] = off + x - v;
}

__global__ __launch_bounds__(256) void k_scan3(int* __restrict__ rowptr,
                                               const int* __restrict__ bsum) {
    int i = blockIdx.x * 256 + threadIdx.x;
    if (i < NN) rowptr[i] += bsum[blockIdx.x];
    if (i == 0) rowptr[NN] = NE;
}

// cursor == counts (still holds per-node counts after scan1); atomicSub gives
// slots count-1..0 -- order within a row is irrelevant for a sum.
__global__ __launch_bounds__(256) void k_fill(const int* __restrict__ edge,
                                              const int* __restrict__ rowptr,
                                              int* __restrict__ cursor,
                                              const float* __restrict__ dinv,
                                              int2* __restrict__ csr) {
    int e = blockIdx.x * 256 + threadIdx.x;
    if (e >= NE) return;
    int s = edge[e], d = edge[NE + e];
    int slot = atomicSub(&cursor[d], 1) - 1;
    csr[rowptr[d] + slot] = make_int2(s, __float_as_int(dinv[s] * dinv[d]));
}

// ================= one-time weight split =================
// W_stack [8][128 k][128 n] fp32 -> Wt4 [8][3 planes][8 ks][128 n][16] bf16.

__global__ __launch_bounds__(256) void k_split_w(const float* __restrict__ Wst,
                                                 ushort* __restrict__ Wt4) {
    int i = blockIdx.x * 256 + threadIdx.x;
    if (i >= 8 * HID * HID) return;
    int l = i >> 14;
    int k = (i >> 7) & 127;
    int n = i & 127;
    ushort h, m, lo;
    split3(Wst[i], h, m, lo);
    int ks = k >> 4, r = k & 15;
    size_t base = ((((size_t)l * 3) * 8 + ks) * 128 + n) * 16 + r;
    const size_t pstride = (size_t)8 * 128 * 16;  // one plane = 16384 ushort
    Wt4[base] = h;
    Wt4[base + pstride] = m;
    Wt4[base + 2 * pstride] = lo;
}

// ========== standalone dense GEMM (layer 0 only): H[NN,128] @ W -> T ==========

__global__ __launch_bounds__(256) void k_mfma_gemm(const float* __restrict__ H,
                                                   const ushort* __restrict__ Wt,
                                                   float* __restrict__ T) {
    int tid = threadIdx.x;
    int lane = tid & 63, w = tid >> 6;
    int l31 = lane & 31, lh = lane >> 5;
    int rowbase = blockIdx.x * 128;

    int grow = rowbase + w * 32 + l31;
    if (grow >= NN) grow = NN - 1;
    const float* arow = H + (size_t)grow * HID + lh * 8;
    const ushort* wbase = Wt + (size_t)l31 * 16 + lh * 8;

    f32x16 acc[4] = {};

#pragma unroll 2
    for (int s = 0; s < 8; ++s) {
        const float4* ap = (const float4*)(arow + s * 16);
        float4 f0 = ap[0], f1 = ap[1];
        float av[8] = {f0.x, f0.y, f0.z, f0.w, f1.x, f1.y, f1.z, f1.w};
        union { ushort u[8]; bf16x8 v; } ah, am, al;
#pragma unroll
        for (int q = 0; q < 8; ++q) split3(av[q], ah.u[q], am.u[q], al.u[q]);

        uint4 bf[3][4];
#pragma unroll
        for (int p = 0; p < 3; ++p)
#pragma unroll
            for (int c = 0; c < 4; ++c)
                bf[p][c] = *(const uint4*)(wbase + (((size_t)p * 8 + s) * 128 + c * 32) * 16);

#pragma unroll
        for (int c = 0; c < 4; ++c)
            acc[c] = __builtin_amdgcn_mfma_f32_32x32x16_bf16(ah.v, *(const bf16x8*)&bf[0][c], acc[c], 0, 0, 0);
#pragma unroll
        for (int c = 0; c < 4; ++c)
            acc[c] = __builtin_amdgcn_mfma_f32_32x32x16_bf16(ah.v, *(const bf16x8*)&bf[1][c], acc[c], 0, 0, 0);
#pragma unroll
        for (int c = 0; c < 4; ++c)
            acc[c] = __builtin_amdgcn_mfma_f32_32x32x16_bf16(am.v, *(const bf16x8*)&bf[0][c], acc[c], 0, 0, 0);
#pragma unroll
        for (int c = 0; c < 4; ++c)
            acc[c] = __builtin_amdgcn_mfma_f32_32x32x16_bf16(ah.v, *(const bf16x8*)&bf[2][c], acc[c], 0, 0, 0);
#pragma unroll
        for (int c = 0; c < 4; ++c)
            acc[c] = __builtin_amdgcn_mfma_f32_32x32x16_bf16(am.v, *(const bf16x8*)&bf[1][c], acc[c], 0, 0, 0);
#pragma unroll
        for (int c = 0; c < 4; ++c)
            acc[c] = __builtin_amdgcn_mfma_f32_32x32x16_bf16(al.v, *(const bf16x8*)&bf[0][c], acc[c], 0, 0, 0);
    }

#pragma unroll
    for (int c = 0; c < 4; ++c)
#pragma unroll
        for (int reg = 0; reg < 16; ++reg) {
            int r = (reg & 3) + 8 * (reg >> 2) + 4 * lh;
            int gr = rowbase + w * 32 + r;
            if (gr < NN)
                T[(size_t)gr * HID + c * 32 + l31] = acc[c][reg];
        }
}

// ========== FUSED: gather(layer l) -> H in LDS -> GEMM W_{l+1} -> Tout ==========
// 256 threads, 64 nodes/block -> Hs = 32 KB -> 5 blocks/CU (vs 2 at 64 KB).
// Phase 1: wave w gathers nodes [16w,16w+16) (2 slots x 32 lanes, unroll-4
// prefetch, bias+ELU), writes fp32 rows to LDS with per-16B XOR swizzle.
// Phase 2: wave w = rowgroup (w>>1) x colhalf (w&1): 32 rows x 64 cols, A from
// LDS + split3 in-register, B streamed from Wt4 (L2-resident).

__global__ __launch_bounds__(256, 4) void k_fused(const float* __restrict__ Tin,
                                                  const ushort* __restrict__ Wt,
                                                  const int* __restrict__ rowptr,
                                                  const int2* __restrict__ csr,
                                                  const float* __restrict__ dinv,
                                                  const float* __restrict__ bias,
                                                  float* __restrict__ Tout) {
    __shared__ float Hs[64 * 128];  // 32 KB
    int tid = threadIdx.x;
    int lane = tid & 63, w = tid >> 6;  // 4 waves
    int slot = lane >> 5, l31 = lane & 31;
    int rowbase = blockIdx.x * 64;

    float4 bv = ((const float4*)bias)[l31];

    // ---- phase 1: gather 16 nodes per wave ----
    for (int i = 0; i < 16; ++i) {
        int lrow = w * 16 + i;
        int node = rowbase + lrow;
        if (node >= NN) node = NN - 1;
        int beg = rowptr[node], end = rowptr[node + 1];
        float sn = dinv[node];

        float4 acc = {0.f, 0.f, 0.f, 0.f};
        if (slot == 1) {
            float4 tv = ((const float4*)(Tin + (size_t)node * HID))[l31];
            float s2 = sn * sn;
            acc.x = s2 * tv.x + bv.x;
            acc.y = s2 * tv.y + bv.y;
            acc.z = s2 * tv.z + bv.z;
            acc.w = s2 * tv.w + bv.w;
        }

        const int2 zed = make_int2(0, 0);
        int p = beg + slot;
        int2 e0 = (p < end) ? csr[p] : zed;
        int2 e1 = (p + 2 < end) ? csr[p + 2] : zed;
        int2 e2 = (p + 4 < end) ? csr[p + 4] : zed;
        int2 e3 = (p + 6 < end) ? csr[p + 6] : zed;
        for (; p < end; p += 8) {
            float4 u0 = ((const float4*)(Tin + (size_t)e0.x * HID))[l31];
            float4 u1 = ((const float4*)(Tin + (size_t)e1.x * HID))[l31];
            float4 u2 = ((const float4*)(Tin + (size_t)e2.x * HID))[l31];
            float4 u3 = ((const float4*)(Tin + (size_t)e3.x * HID))[l31];
            float w0 = __int_as_float(e0.y), w1 = __int_as_float(e1.y);
            float w2 = __int_as_float(e2.y), w3 = __int_as_float(e3.y);
            e0 = (p + 8 < end) ? csr[p + 8] : zed;
            e1 = (p + 10 < end) ? csr[p + 10] : zed;
            e2 = (p + 12 < end) ? csr[p + 12] : zed;
            e3 = (p + 14 < end) ? csr[p + 14] : zed;
            acc.x += w0 * u0.x; acc.y += w0 * u0.y; acc.z += w0 * u0.z; acc.w += w0 * u0.w;
            acc.x += w1 * u1.x; acc.y += w1 * u1.y; acc.z += w1 * u1.z; acc.w += w1 * u1.w;
            acc.x += w2 * u2.x; acc.y += w2 * u2.y; acc.z += w2 * u2.z; acc.w += w2 * u2.w;
            acc.x += w3 * u3.x; acc.y += w3 * u3.y; acc.z += w3 * u3.z; acc.w += w3 * u3.w;
        }

        acc.x += __shfl_xor(acc.x, 32, 64);
        acc.y += __shfl_xor(acc.y, 32, 64);
        acc.z += __shfl_xor(acc.z, 32, 64);
        acc.w += __shfl_xor(acc.w, 32, 64);

        if (slot == 0) {
            float4 r = acc;
            r.x = r.x > 0.f ? r.x : expm1f(r.x);
            r.y = r.y > 0.f ? r.y : expm1f(r.y);
            r.z = r.z > 0.f ? r.z : expm1f(r.z);
            r.w = r.w > 0.f ? r.w : expm1f(r.w);
            int byte = lrow * 512 + l31 * 16;
            byte ^= (lrow & 7) << 4;
            *(float4*)((char*)Hs + byte) = r;
        }
    }
    __syncthreads();

    // ---- phase 2: GEMM 64x128 tile over 4 waves ----
    int lh = slot;                    // k-octet selector
    int rloc = (w >> 1) * 32 + l31;   // local A row
    int colh = w & 1;                 // column half (64)
    const ushort* wbase = Wt + ((size_t)(colh * 64) + l31) * 16 + lh * 8;

    f32x16 acc2[2] = {};

#pragma unroll 2
    for (int s = 0; s < 8; ++s) {
        int byte = rloc * 512 + s * 64 + lh * 32;
        int sw = (rloc & 7) << 4;
        float4 f0 = *(const float4*)((const char*)Hs + (byte ^ sw));
        float4 f1 = *(const float4*)((const char*)Hs + ((byte + 16) ^ sw));
        float av[8] = {f0.x, f0.y, f0.z, f0.w, f1.x, f1.y, f1.z, f1.w};
        union { ushort u[8]; bf16x8 v; } ah, am, al;
#pragma unroll
        for (int q = 0; q < 8; ++q) split3(av[q], ah.u[q], am.u[q], al.u[q]);

        uint4 bf[3][2];
#pragma unroll
        for (int p = 0; p < 3; ++p)
#pragma unroll
            for (int c = 0; c < 2; ++c)
                bf[p][c] = *(const uint4*)(wbase + (((size_t)p * 8 + s) * 128 + c * 32) * 16);

#pragma unroll
        for (int c = 0; c < 2; ++c)
            acc2[c] = __builtin_amdgcn_mfma_f32_32x32x16_bf16(ah.v, *(const bf16x8*)&bf[0][c], acc2[c], 0, 0, 0);
#pragma unroll
        for (int c = 0; c < 2; ++c)
            acc2[c] = __builtin_amdgcn_mfma_f32_32x32x16_bf16(ah.v, *(const bf16x8*)&bf[1][c], acc2[c], 0, 0, 0);
#pragma unroll
        for (int c = 0; c < 2; ++c)
            acc2[c] = __builtin_amdgcn_mfma_f32_32x32x16_bf16(am.v, *(const bf16x8*)&bf[0][c], acc2[c], 0, 0, 0);
#pragma unroll
        for (int c = 0; c < 2; ++c)
            acc2[c] = __builtin_amdgcn_mfma_f32_32x32x16_bf16(ah.v, *(const bf16x8*)&bf[2][c], acc2[c], 0, 0, 0);
#pragma unroll
        for (int c = 0; c < 2; ++c)
            acc2[c] = __builtin_amdgcn_mfma_f32_32x32x16_bf16(am.v, *(const bf16x8*)&bf[1][c], acc2[c], 0, 0, 0);
#pragma unroll
        for (int c = 0; c < 2; ++c)
            acc2[c] = __builtin_amdgcn_mfma_f32_32x32x16_bf16(al.v, *(const bf16x8*)&bf[0][c], acc2[c], 0, 0, 0);
    }

    // C/D layout: col = lane&31, row = (reg&3) + 8*(reg>>2) + 4*(lane>>5)
#pragma unroll
    for (int c = 0; c < 2; ++c)
#pragma unroll
        for (int reg = 0; reg < 16; ++reg) {
            int r = (reg & 3) + 8 * (reg >> 2) + 4 * lh;
            int gr = rowbase + (w >> 1) * 32 + r;
            if (gr < NN)
                Tout[(size_t)gr * HID + colh * 64 + c * 32 + l31] = acc2[c][reg];
        }
}

// ============ standalone gather (last hidden layer): T -> H global ============

__global__ __launch_bounds__(256) void k_gather_agg(const float* __restrict__ T,
                                                    float* __restrict__ Hout,
                                                    const int* __restrict__ rowptr,
                                                    const int2* __restrict__ csr,
                                                    const float* __restrict__ dinv,
                                                    const float* __restrict__ bias) {
    int lane = threadIdx.x & 63;
    int node = (blockIdx.x * 256 + threadIdx.x) >> 6;
    if (node >= NN) return;
    int slot = lane >> 5, l31 = lane & 31;

    int beg = rowptr[node], end = rowptr[node + 1];
    float sn = dinv[node];

    float4 acc = {0.f, 0.f, 0.f, 0.f};
    if (slot == 1) {
        float4 tv = ((const float4*)(T + (size_t)node * HID))[l31];
        float4 bv = ((const float4*)bias)[l31];
        float s2 = sn * sn;
        acc.x = s2 * tv.x + bv.x;
        acc.y = s2 * tv.y + bv.y;
        acc.z = s2 * tv.z + bv.z;
        acc.w = s2 * tv.w + bv.w;
    }

    const int2 zed = make_int2(0, 0);
    int p = beg + slot;
    int2 e0 = (p < end) ? csr[p] : zed;
    int2 e1 = (p + 2 < end) ? csr[p + 2] : zed;
    int2 e2 = (p + 4 < end) ? csr[p + 4] : zed;
    int2 e3 = (p + 6 < end) ? csr[p + 6] : zed;
    for (; p < end; p += 8) {
        float4 u0 = ((const float4*)(T + (size_t)e0.x * HID))[l31];
        float4 u1 = ((const float4*)(T + (size_t)e1.x * HID))[l31];
        float4 u2 = ((const float4*)(T + (size_t)e2.x * HID))[l31];
        float4 u3 = ((const float4*)(T + (size_t)e3.x * HID))[l31];
        float w0 = __int_as_float(e0.y), w1 = __int_as_float(e1.y);
        float w2 = __int_as_float(e2.y), w3 = __int_as_float(e3.y);
        e0 = (p + 8 < end) ? csr[p + 8] : zed;
        e1 = (p + 10 < end) ? csr[p + 10] : zed;
        e2 = (p + 12 < end) ? csr[p + 12] : zed;
        e3 = (p + 14 < end) ? csr[p + 14] : zed;
        acc.x += w0 * u0.x; acc.y += w0 * u0.y; acc.z += w0 * u0.z; acc.w += w0 * u0.w;
        acc.x += w1 * u1.x; acc.y += w1 * u1.y; acc.z += w1 * u1.z; acc.w += w1 * u1.w;
        acc.x += w2 * u2.x; acc.y += w2 * u2.y; acc.z += w2 * u2.z; acc.w += w2 * u2.w;
        acc.x += w3 * u3.x; acc.y += w3 * u3.y; acc.z += w3 * u3.z; acc.w += w3 * u3.w;
    }

    acc.x += __shfl_xor(acc.x, 32, 64);
    acc.y += __shfl_xor(acc.y, 32, 64);
    acc.z += __shfl_xor(acc.z, 32, 64);
    acc.w += __shfl_xor(acc.w, 32, 64);

    if (slot == 0) {
        float4 r = acc;
        r.x = r.x > 0.f ? r.x : expm1f(r.x);
        r.y = r.y > 0.f ? r.y : expm1f(r.y);
        r.z = r.z > 0.f ? r.z : expm1f(r.z);
        r.w = r.w > 0.f ? r.w : expm1f(r.w);
        ((float4*)(Hout + (size_t)node * HID))[l31] = r;
    }
}

// ================= output layer (128 -> 10) =================

__global__ __launch_bounds__(256) void k_matmul_out(const float* __restrict__ H,
                                                    const float* __restrict__ W,
                                                    float* __restrict__ T2) {
    __shared__ float Ws[128 * 11];
    int tid = threadIdx.x;
    for (int m = tid; m < HID * NCLS; m += 256) {
        int k = m / NCLS, c = m - k * NCLS;
        Ws[k * 11 + c] = W[m];
    }
    __syncthreads();
    int row = (blockIdx.x * 256 + tid) >> 4;
    int c16 = tid & 15;
    if (row >= NN) return;
    const float4* h4 = (const float4*)(H + (size_t)row * HID) + c16 * 2;
    float4 h0 = h4[0], h1 = h4[1];
    float hv[8] = {h0.x, h0.y, h0.z, h0.w, h1.x, h1.y, h1.z, h1.w};
    float acc[NCLS];
#pragma unroll
    for (int c = 0; c < NCLS; ++c) acc[c] = 0.f;
#pragma unroll
    for (int j = 0; j < 8; ++j) {
        const float* wr = &Ws[(c16 * 8 + j) * 11];
#pragma unroll
        for (int c = 0; c < NCLS; ++c) acc[c] += hv[j] * wr[c];
    }
#pragma unroll
    for (int off = 8; off >= 1; off >>= 1) {
#pragma unroll
        for (int c = 0; c < NCLS; ++c) acc[c] += __shfl_xor(acc[c], off, 16);
    }
    if (c16 < NCLS) T2[(size_t)row * T2S + c16] = acc[c16];
}

__global__ __launch_bounds__(256) void k_gather_out(const float* __restrict__ T2,
                                                    float* __restrict__ out,
                                                    const int* __restrict__ rowptr,
                                                    const int2* __restrict__ csr,
                                                    const float* __restrict__ dinv,
                                                    const float* __restrict__ bias) {
    int lane = threadIdx.x & 63;
    int node = (blockIdx.x * 256 + threadIdx.x) >> 6;
    if (node >= NN) return;
    int slot = lane >> 4, c = lane & 15;
    int beg = rowptr[node], end = rowptr[node + 1];
    float acc = 0.f;
    if (c < NCLS) {
        for (int i = beg + slot; i < end; i += 4) {
            int2 e = csr[i];
            acc += __int_as_float(e.y) * T2[(size_t)e.x * T2S + c];
        }
    }
    acc += __shfl_xor(acc, 16, 64);
    acc += __shfl_xor(acc, 32, 64);
    if (slot == 0 && c < NCLS) {
        float sn = dinv[node];
        sn *= sn;
        out[node * NCLS + c] = acc + sn * T2[(size_t)node * T2S + c] + bias[c];
    }
}

// ================= launch =================

extern "C" void kernel_launch(void* const* d_in, const int* in_sizes, int n_in,
                              void* d_out, int out_size, void* d_ws, size_t ws_size,
                              hipStream_t stream) {
    (void)in_sizes; (void)n_in; (void)out_size; (void)ws_size;
    const float* x       = (const float*)d_in[0];
    const int*   edge    = (const int*)d_in[1];   // [2, NE] int32
    const float* W_stack = (const float*)d_in[2];
    const float* b_stack = (const float*)d_in[3];
    const float* W_out   = (const float*)d_in[4];
    const float* b_out   = (const float*)d_in[5];
    float* out = (float*)d_out;

    char* ws = (char*)d_ws;
    const size_t bigbuf = (size_t)NN * HID * sizeof(float);  // 25.6 MB
    float* X      = (float*)ws;
    float* Y      = (float*)(ws + bigbuf);
    char*  p      = ws + 2 * bigbuf;
    int2*  csr    = (int2*)p;              p += sizeof(int2) * NE;
    float* dinv   = (float*)p;             p += sizeof(float) * NN;
    int*   rowptr = (int*)p;               p += sizeof(int) * (NN + 1);
    int*   counts = (int*)p;               p += sizeof(int) * NN;    // reused as cursor
    int*   bsum   = (int*)p;               p += sizeof(int) * 256;
    p = (char*)(((size_t)p + 15) & ~(size_t)15);
    ushort* Wt4 = (ushort*)p;  p += sizeof(ushort) * 8 * 3 * HID * HID;  // 786 KB
    float* T2b  = (float*)p;   p += sizeof(float) * NN * T2S;            // 3.2 MB

    const int NB_N  = (NN + 255) / 256;
    const int NB_E  = (NE + 255) / 256;
    const int NB_G  = (NN + 127) / 128;        // 391 GEMM tiles (layer 0)
    const int NB_F  = (NN + 63) / 64;          // 782 fused tiles
    const int NB_A  = (NN * 64 + 255) / 256;
    const int NB_O  = (NN * 16 + 255) / 256;
    const int NB_SW = (8 * HID * HID + 255) / 256;

    // ---- CSR build (per call) ----
    hipMemsetAsync(counts, 0, sizeof(int) * NN, stream);
    k_count<<<NB_E, 256, 0, stream>>>(edge, counts);
    k_scan1<<<NB_N, 256, 0, stream>>>(counts, rowptr, bsum, dinv);
    k_scan2<<<1, 256, 0, stream>>>(bsum, NB_N);
    k_scan3<<<NB_N, 256, 0, stream>>>(rowptr, bsum);
    k_fill<<<NB_E, 256, 0, stream>>>(edge, rowptr, counts, dinv, csr);

    // ---- one-time weight split ----
    k_split_w<<<NB_SW, 256, 0, stream>>>(W_stack, Wt4);

    // ---- layer 0 GEMM: T_0 = x . W0 ----
    k_mfma_gemm<<<NB_G, 256, 0, stream>>>(x, Wt4, Y);

    // ---- fused layers: gather(l) + GEMM W_{l+1}, l = 0..6 ----
    float* cur = Y;
    float* nxt = X;
    for (int l = 0; l < 7; ++l) {
        k_fused<<<NB_F, 256, 0, stream>>>(cur, Wt4 + (size_t)(l + 1) * 3 * HID * HID,
                                          rowptr, csr, dinv,
                                          b_stack + (size_t)l * HID, nxt);
        float* t = cur; cur = nxt; nxt = t;
    }

    // ---- last hidden gather (bias 7) -> H global ----
    k_gather_agg<<<NB_A, 256, 0, stream>>>(cur, nxt, rowptr, csr, dinv,
                                           b_stack + (size_t)7 * HID);

    // ---- output layer ----
    k_matmul_out<<<NB_O, 256, 0, stream>>>(nxt, W_out, T2b);
    k_gather_out<<<NB_A, 256, 0, stream>>>(T2b, out, rowptr, csr, dinv, b_out);
}